// Round 13
// baseline (529.907 us; speedup 1.0000x reference)
//
#include <hip/hip_runtime.h>

#define T_STEPS 4
#define BATCH   8
#define C_IN    64
#define C_OUT   64
#define HH      128
#define WW      128
#define TH      8           // block tile height (2 wave-strips of 4)
#define TW      16
#define ROWS    (TH + 2)    // 10
#define COLS    18          // TW + halo
#define CPAD    68          // ci dim padded: stride mod 32 == 4 -> b128 conflict-free

// f32 rounding of math.exp(-0.5)
#define DECAY_F32 0.6065306597126334f

// Weight re-layout: w[co][ci][ky][kx] -> wt[j][ci][co], j = ky*3+kx
__global__ void wt_build_kernel(const float* __restrict__ w, float* __restrict__ wt) {
    int tid = blockIdx.x * blockDim.x + threadIdx.x;
    if (tid >= 9 * C_IN * C_OUT) return;
    int co = tid & 63;
    int ci = (tid >> 6) & 63;
    int j  = tid >> 12;
    wt[tid] = w[(co * C_IN + ci) * 9 + j];
}

// Exact replica of the reference f32 arithmetic (probe-verified variant A):
// per output: seq FMA chain over (ky,kx, ci-innermost); cb = acc+bias;
// vt = v*DECAY + cb (separate rounded mul/add); spike = vt>1; soft reset.
//
// Block = 512 thr = 8 waves. Wave w: y-strip sy=(w>>2)*4, co base=(w&3)*16.
// Lane owns ONE pixel (y=lane&3, x=lane>>2) and 16 c_out.
// x tile in LDS is ci-INNERMOST: sx[row][col][ci(68)] so each ds_read_b128
// fetches 4 consecutive ci for the lane's pixel (4x fewer LDS ops, conflict-
// free: col stride 68 = 4 mod 32). Weights via wave-uniform s_load (SGPR),
// bias via SGPR. LDS 48960 B -> 3 blocks/CU; VGPR target <= 64 -> 24 waves/CU.
__global__ __launch_bounds__(512) void snn_exact_kernel(
    const float* __restrict__ x,    // [T,B,C_IN,H,W]
    const float* __restrict__ wt,   // [9][C_IN][C_OUT]
    const float* __restrict__ bias, // [C_OUT]
    float* __restrict__ out)        // [T,B,C_OUT,H,W]
{
    __shared__ __align__(16) float sx[ROWS * COLS * CPAD];   // 48960 B

    const int tid  = threadIdx.x;
    const int wid  = __builtin_amdgcn_readfirstlane(tid >> 6); // 0..7 (SGPR)
    const int lane = tid & 63;
    const int y    = lane & 3;          // 0..3 within strip
    const int xcol = lane >> 2;         // 0..15
    const int sy   = (wid >> 2) << 2;   // strip base: 0 or 4
    const int cob  = (wid & 3) << 4;    // wave's co base: 0,16,32,48
    const int b    = blockIdx.z;
    const int gy0  = blockIdx.y * TH;
    const int gx0  = blockIdx.x * TW;

    const float* bp = bias + cob;       // wave-uniform -> SGPR loads

    // per-lane x base (words): pixel (sy+y, xcol); all tap/ci offsets are immediates
    const float* xbase = &sx[((sy + y) * COLS + xcol) * CPAD];

    float v[16];
#pragma unroll
    for (int o = 0; o < 16; ++o) v[o] = 0.0f;

    for (int t = 0; t < T_STEPS; ++t) {
        __syncthreads();  // prior t's reads done before overwrite
        const float* xsrc = x + ((size_t)(t * BATCH + b) * C_IN) * (HH * WW);
        for (int e = tid; e < C_IN * ROWS * COLS; e += 512) {
            int ci  = e / (ROWS * COLS);
            int rem = e - ci * (ROWS * COLS);
            int row = rem / COLS;
            int col = rem - row * COLS;
            int gy  = gy0 + row - 1;
            int gx  = gx0 + col - 1;
            float val = 0.0f;
            if ((unsigned)gy < (unsigned)HH && (unsigned)gx < (unsigned)WW)
                val = xsrc[ci * (HH * WW) + gy * WW + gx];
            sx[(row * COLS + col) * CPAD + ci] = val;
        }
        __syncthreads();

        float acc[16];
#pragma unroll
        for (int o = 0; o < 16; ++o) acc[o] = 0.0f;

// One conv tap: ci 0..63 in chunks of 4 (strictly ascending -> exact chain
// order). Per chunk: one ds_read_b128 (4 ci) + 4x16 FMA with SGPR weights.
#define TAP(KY, KX)                                                                   \
        {                                                                             \
            const float* wj = wt + ((KY) * 3 + (KX)) * (C_IN * C_OUT) + cob;          \
            const float* xt = xbase + ((KY) * COLS + (KX)) * CPAD;                    \
            _Pragma("unroll 2")                                                       \
            for (int ci0 = 0; ci0 < C_IN; ci0 += 4) {                                 \
                const float4 xv = *reinterpret_cast<const float4*>(xt + ci0);         \
                const float xq[4] = {xv.x, xv.y, xv.z, xv.w};                         \
                _Pragma("unroll")                                                     \
                for (int k = 0; k < 4; ++k) {                                         \
                    const float* wp = wj + ((ci0 + k) << 6);                          \
                    _Pragma("unroll")                                                 \
                    for (int o = 0; o < 16; ++o)                                      \
                        acc[o] = fmaf(xq[k], wp[o], acc[o]);                          \
                }                                                                     \
            }                                                                         \
        }

        TAP(0, 0) TAP(0, 1) TAP(0, 2)
        TAP(1, 0) TAP(1, 1) TAP(1, 2)
        TAP(2, 0) TAP(2, 1) TAP(2, 2)
#undef TAP

        // ---- LIF update (exact f32 op sequence) + spike store ----
        float* obase = out + ((size_t)(t * BATCH + b) * C_OUT + cob) * (HH * WW)
                     + (gy0 + sy + y) * WW + gx0 + xcol;
#pragma unroll
        for (int o = 0; o < 16; ++o) {
            float cb = __fadd_rn(acc[o], bp[o]);                  // conv + bias (SGPR)
            float vt = __fadd_rn(__fmul_rn(v[o], DECAY_F32), cb); // v*DECAY + cb
            bool fire = vt > 1.0f;
            v[o] = fire ? 0.0f : vt;                              // soft reset
            obase[(size_t)o * (HH * WW)] = fire ? 1.0f : 0.0f;
        }
    }
}

extern "C" void kernel_launch(void* const* d_in, const int* in_sizes, int n_in,
                              void* d_out, int out_size, void* d_ws, size_t ws_size,
                              hipStream_t stream) {
    const float* x    = (const float*)d_in[0];
    const float* w    = (const float*)d_in[1];
    const float* bias = (const float*)d_in[2];
    float* out = (float*)d_out;
    float* wt  = (float*)d_ws;   // 9*64*64*4 = 147456 bytes

    hipLaunchKernelGGL(wt_build_kernel, dim3((9 * C_IN * C_OUT + 255) / 256), dim3(256), 0, stream, w, wt);
    hipLaunchKernelGGL(snn_exact_kernel, dim3(WW / TW, HH / TH, BATCH), dim3(512), 0, stream,
                       x, wt, bias, out);
}

// Round 14
// 512.065 us; speedup vs baseline: 1.0348x; 1.0348x over previous
//
#include <hip/hip_runtime.h>

#define T_STEPS 4
#define BATCH   8
#define C_IN    64
#define C_OUT   64
#define HH      128
#define WW      128
#define TH      8
#define TW      8
#define ROWS    (TH + 2)    // 10
#define COLS    (TW + 2)    // 10
#define NPOS    (ROWS * COLS)   // 100
#define CPAD    68          // ci stride (words): 68 = 4 mod 32 -> conflict-free b128

// f32 rounding of math.exp(-0.5)
#define DECAY_F32 0.6065306597126334f

// Weight re-layout: w[co][ci][ky][kx] -> wt[j][ci][co], j = ky*3+kx
__global__ void wt_build_kernel(const float* __restrict__ w, float* __restrict__ wt) {
    int tid = blockIdx.x * blockDim.x + threadIdx.x;
    if (tid >= 9 * C_IN * C_OUT) return;
    int co = tid & 63;
    int ci = (tid >> 6) & 63;
    int j  = tid >> 12;
    wt[tid] = w[(co * C_IN + ci) * 9 + j];
}

// Exact replica of the reference f32 arithmetic (probe-verified variant A):
// per output: seq FMA chain over (ky,kx, ci-innermost); cb = acc+bias;
// vt = v*DECAY + cb (separate rounded mul/add); spike = vt>1; soft reset.
//
// Block = 256 thr = 4 waves; wave w owns co [16w,16w+16). Lane owns ONE pixel
// of the 8x8 tile (x=lane&7, y=lane>>3) and 16 c_out.
// LDS x tile is ci-innermost: sx[pos][ci(68)], pos = row*10+col. Per (tap,
// ci-quad): one ds_read_b128 (phase groups of 8 lanes cover all 32 banks ->
// conflict-free) + 64 FMA with SGPR-broadcast weights (wave-uniform s_load).
// LDS 27200 B -> 5 blocks/CU -> 20 waves/CU.
__global__ __launch_bounds__(256, 5) void snn_exact_kernel(
    const float* __restrict__ x,    // [T,B,C_IN,H,W]
    const float* __restrict__ wt,   // [9][C_IN][C_OUT]
    const float* __restrict__ bias, // [C_OUT]
    float* __restrict__ out)        // [T,B,C_OUT,H,W]
{
    __shared__ __align__(16) float sx[NPOS * CPAD];   // 27200 B

    const int tid  = threadIdx.x;
    const int wid  = __builtin_amdgcn_readfirstlane(tid >> 6); // 0..3 (SGPR)
    const int lane = tid & 63;
    const int xq_  = lane & 7;          // 0..7
    const int yq_  = lane >> 3;         // 0..7
    const int cob  = wid << 4;          // wave's co base: 0,16,32,48
    const int b    = blockIdx.z;
    const int gy0  = blockIdx.y * TH;
    const int gx0  = blockIdx.x * TW;

    const float* bp = bias + cob;       // wave-uniform -> SGPR

    float v[16];
#pragma unroll
    for (int o = 0; o < 16; ++o) v[o] = 0.0f;

    for (int t = 0; t < T_STEPS; ++t) {
        __syncthreads();  // prior t's reads done before overwrite
        const float* xsrc = x + ((size_t)(t * BATCH + b) * C_IN) * (HH * WW);
        // stage: e = cig*100 + pos; pos-fastest -> coalesced global reads per
        // ci-plane and 2-way-max LDS write banks. Each thread writes a b128
        // (4 consecutive ci) at its pos.
        for (int e = tid; e < NPOS * (C_IN / 4); e += 256) {
            int cig = e / NPOS;             // 0..15 -> ci0 = 4*cig
            int pos = e - cig * NPOS;       // 0..99
            int row = pos / COLS;
            int col = pos - row * COLS;
            int gy  = gy0 + row - 1;
            int gx  = gx0 + col - 1;
            float4 val = {0.f, 0.f, 0.f, 0.f};
            if ((unsigned)gy < (unsigned)HH && (unsigned)gx < (unsigned)WW) {
                const float* g = xsrc + (size_t)(cig << 2) * (HH * WW) + gy * WW + gx;
                val.x = g[0];
                val.y = g[HH * WW];
                val.z = g[2 * HH * WW];
                val.w = g[3 * HH * WW];
            }
            *reinterpret_cast<float4*>(&sx[pos * CPAD + (cig << 2)]) = val;
        }
        __syncthreads();

        float acc[16];
#pragma unroll
        for (int o = 0; o < 16; ++o) acc[o] = 0.0f;

// One conv tap: ci 0..63 in ascending quads (exact chain order).
// Per quad: one ds_read_b128 + 4x16 FMA with SGPR weights.
#define TAP(KY, KX)                                                                   \
        {                                                                             \
            const float* wj = wt + ((KY) * 3 + (KX)) * (C_IN * C_OUT) + cob;          \
            const float* xt = &sx[((yq_ + (KY)) * COLS + (xq_ + (KX))) * CPAD];       \
            _Pragma("unroll 2")                                                       \
            for (int ci0 = 0; ci0 < C_IN; ci0 += 4) {                                 \
                const float4 xv = *reinterpret_cast<const float4*>(xt + ci0);         \
                const float xq[4] = {xv.x, xv.y, xv.z, xv.w};                         \
                _Pragma("unroll")                                                     \
                for (int k = 0; k < 4; ++k) {                                         \
                    const float* wp = wj + ((ci0 + k) << 6);                          \
                    _Pragma("unroll")                                                 \
                    for (int o = 0; o < 16; ++o)                                      \
                        acc[o] = fmaf(xq[k], wp[o], acc[o]);                          \
                }                                                                     \
            }                                                                         \
        }

        TAP(0, 0) TAP(0, 1) TAP(0, 2)
        TAP(1, 0) TAP(1, 1) TAP(1, 2)
        TAP(2, 0) TAP(2, 1) TAP(2, 2)
#undef TAP

        // ---- LIF update (exact f32 op sequence) + spike store ----
        float* obase = out + ((size_t)(t * BATCH + b) * C_OUT + cob) * (HH * WW)
                     + (gy0 + yq_) * WW + gx0 + xq_;
#pragma unroll
        for (int o = 0; o < 16; ++o) {
            float cb = __fadd_rn(acc[o], bp[o]);                  // conv + bias (SGPR)
            float vt = __fadd_rn(__fmul_rn(v[o], DECAY_F32), cb); // v*DECAY + cb
            bool fire = vt > 1.0f;
            v[o] = fire ? 0.0f : vt;                              // soft reset
            obase[(size_t)o * (HH * WW)] = fire ? 1.0f : 0.0f;
        }
    }
}

extern "C" void kernel_launch(void* const* d_in, const int* in_sizes, int n_in,
                              void* d_out, int out_size, void* d_ws, size_t ws_size,
                              hipStream_t stream) {
    const float* x    = (const float*)d_in[0];
    const float* w    = (const float*)d_in[1];
    const float* bias = (const float*)d_in[2];
    float* out = (float*)d_out;
    float* wt  = (float*)d_ws;   // 9*64*64*4 = 147456 bytes

    hipLaunchKernelGGL(wt_build_kernel, dim3((9 * C_IN * C_OUT + 255) / 256), dim3(256), 0, stream, w, wt);
    hipLaunchKernelGGL(snn_exact_kernel, dim3(WW / TW, HH / TH, BATCH), dim3(256), 0, stream,
                       x, wt, bias, out);
}